// Round 3
// baseline (347.092 us; speedup 1.0000x reference)
//
#include <hip/hip_runtime.h>

#define NB 32
#define CCH 64
#define HH 96
#define WWID 96
#define HWP (HH*WWID)   // 9216
#define K7 448

// ws layout (float offsets):
//   t2p : [32][16][64][64] fp32 partials     = 2,097,152
//   t5  : [32][64][64]                       =   131,072
//   t8t : [32][64][448] bf16 (k'=kk*64+c7)   =   458,752 floats of space
//   t6  : [32][9216]                         =   294,912
//   t9  : [32][64]                           =     2,048
//   xt  : [32][96][96][64] bf16 (chan-minor) = 9,437,184 floats of space
// total = 49.7 MB
#define OFF_T5 2097152
#define OFF_T8 2228224
#define OFF_T6 2686976
#define OFF_T9 2981888
#define OFF_XT 2983936

typedef __attribute__((ext_vector_type(8))) short short8;
typedef __attribute__((ext_vector_type(4))) float floatx4;

__device__ __forceinline__ short f2bf(float x) {
    unsigned u = __float_as_uint(x);
    unsigned r = (u + 0x7FFF + ((u >> 16) & 1)) >> 16;  // RNE
    return (short)r;
}

// ---------------------------------------------------------------------------
// Kernel XT: xt[n][h][w][c] = bf16(x[n][c][h][w])  (channel-minor transpose)
// LDS tile 64x97 fp32: coalesced read, conflict-free transpose, coalesced write.
// ---------------------------------------------------------------------------
__global__ __launch_bounds__(256) void k_xt(const float* __restrict__ x,
                                            short* __restrict__ xt) {
    int n = blockIdx.y, h = blockIdx.x;
    __shared__ float xl[64][97];
    int t = threadIdx.x;
    const float* xn = x + (size_t)n * CCH * HWP + h * WWID;
#pragma unroll
    for (int i = 0; i < 24; i++) {
        int e = i * 256 + t;            // < 6144
        int c = e / 96, w = e - c * 96;
        xl[c][w] = xn[c * HWP + w];
    }
    __syncthreads();
    short* xtn = xt + ((size_t)n * HH + h) * (WWID * 64);
    int c = t & 63, wg = t >> 6;
#pragma unroll
    for (int i = 0; i < 24; i++) {
        int w = i * 4 + wg;
        xtn[w * 64 + c] = f2bf(xl[c][w]);
    }
}

// ---------------------------------------------------------------------------
// Kernel A: t2 partials via bf16 MFMA, LDS-free.
// t2[n,c,d] = sum_k x[n,c,k] * x[n,d,roll(k)],  K split 16 (1152 each, 12 rows).
// Wave: A-strip c = wv*16+(lane&15); B covers d 0..63 (4 frags). In-reg f2bf.
// roll: row h-1 (wrap), col +1; wrap of col 96->0 fixed via 1 scalar per frag.
// ---------------------------------------------------------------------------
__global__ __launch_bounds__(256) void k_t2(const float* __restrict__ x,
                                            float* __restrict__ t2p) {
    int n = blockIdx.x >> 4, ks = blockIdx.x & 15;
    int t = threadIdx.x;
    int wv = t >> 6, lane = t & 63;
    int q = lane >> 4, m = lane & 15;
    const float* xn = x + (size_t)n * CCH * HWP;
    const float* xa = xn + (wv * 16 + m) * HWP;
    floatx4 acc[4] = {};

    int k0 = ks * 576;
    for (int kc = k0; kc < k0 + 576; kc += 32) {
        int h = kc / 96;
        int w0 = kc - h * 96;            // 0, 32, 64
        int hr = (h == 0) ? (HH - 1) : (h - 1);
        // A fragment: x[c][kc + q*8 .. +7]
        float4 a0 = *(const float4*)(xa + kc + q * 8);
        float4 a1 = *(const float4*)(xa + kc + q * 8 + 4);
        short8 af = {f2bf(a0.x), f2bf(a0.y), f2bf(a0.z), f2bf(a0.w),
                     f2bf(a1.x), f2bf(a1.y), f2bf(a1.z), f2bf(a1.w)};
#pragma unroll
        for (int j = 0; j < 4; j++) {
            const float* xr = xn + (j * 16 + m) * HWP + hr * 96;
            int base = w0 + q * 8;
            float4 b0 = *(const float4*)(xr + base);      // cols base..base+3
            float4 b1 = *(const float4*)(xr + base + 4);  // cols base+4..+7
            int c8 = base + 8;
            float e8 = xr[c8 == 96 ? 0 : c8];             // col wrap fix
            short8 bf = {f2bf(b0.y), f2bf(b0.z), f2bf(b0.w), f2bf(b1.x),
                         f2bf(b1.y), f2bf(b1.z), f2bf(b1.w), f2bf(e8)};
            acc[j] = __builtin_amdgcn_mfma_f32_16x16x32_bf16(af, bf, acc[j], 0, 0, 0);
        }
    }
    // D: row (within wave strip) = q*4+i, col = m
    float* o = t2p + ((size_t)(n * 16 + ks)) * 4096;
#pragma unroll
    for (int j = 0; j < 4; j++)
#pragma unroll
        for (int i = 0; i < 4; i++)
            o[(wv * 16 + q * 4 + i) * 64 + j * 16 + m] = acc[j][i];
}

// ---------------------------------------------------------------------------
// Kernel B1: t5[n,b,c] = p5[b,c] * (sum_slices t2p) / 96
// ---------------------------------------------------------------------------
__global__ __launch_bounds__(256) void k_t5(const float* __restrict__ t2p,
                                            const float* __restrict__ p5,
                                            float* __restrict__ t5) {
    int idx = blockIdx.x * 256 + threadIdx.x;
    int n = idx >> 12, rc = idx & 4095;
    float s = 0.f;
#pragma unroll
    for (int sl = 0; sl < 16; sl++)
        s += t2p[((size_t)n * 16 + sl) * 4096 + rc];
    t5[idx] = s * p5[rc] * (1.0f / 96.0f);
}

// ---------------------------------------------------------------------------
// Kernel B2: t8t[n][c][kk*64+c7] = bf16((1/sqrt(448)) * sum_b t5[n,b,c]*p8[b,k])
// k = c7*7+kk.
// ---------------------------------------------------------------------------
__global__ __launch_bounds__(256) void k_t8(const float* __restrict__ t5,
                                            const float* __restrict__ p8,
                                            short* __restrict__ t8t) {
    int n = blockIdx.y;
    int idx = blockIdx.x * 256 + threadIdx.x;   // [0, 448*64)
    int k = idx >> 6, c = idx & 63;
    const float* t5n = t5 + (size_t)n * 4096;
    float s = 0.f;
#pragma unroll 8
    for (int b = 0; b < 64; b++)
        s += t5n[b * 64 + c] * p8[b * K7 + k];
    int c7 = k / 7, kk = k - c7 * 7;
    t8t[((size_t)n * 64 + c) * K7 + kk * 64 + c7] = f2bf(s * 0.04724555912f);
}

// ---------------------------------------------------------------------------
// Kernel C1: t6[n,h,w] = sum_c p6[c] * dwconv3x3_d2(t1)[n,c,h,w]
// ---------------------------------------------------------------------------
__global__ __launch_bounds__(256) void k_t6(const float* __restrict__ x,
                                            const float* __restrict__ w4,
                                            const float* __restrict__ p6,
                                            float* __restrict__ t6) {
    int n = blockIdx.y;
    int pix = blockIdx.x * 256 + threadIdx.x;   // < 9216
    int h = pix / WWID, w = pix - h * WWID;

    int off9[9];
    float m9[9];
#pragma unroll
    for (int i = 0; i < 3; i++) {
        int gh = h + (i - 1) * 2;
        bool vr = (gh >= 0) && (gh < HH);
        int srow = vr ? ((gh + HH - 1) % HH) * WWID : 0;
        float rm = vr ? 1.f : 0.f;
#pragma unroll
        for (int j = 0; j < 3; j++) {
            int gw = w + (j - 1) * 2;
            bool vc = (gw >= 0) && (gw < WWID);
            int scol = vc ? (gw + 1) % WWID : 0;
            off9[i * 3 + j] = srow + scol;
            m9[i * 3 + j] = vc ? rm : 0.f;
        }
    }
    const float* xn = x + (size_t)n * CCH * HWP;
    float acc = 0.f;
    for (int c = 0; c < CCH; c++) {
        const float* xc = xn + c * HWP;
        float pw = p6[c];
        const float* wc = w4 + c * 9;
#pragma unroll
        for (int ij = 0; ij < 9; ij++) {
            float wm = wc[ij] * pw * m9[ij];
            acc = fmaf(wm, xc[off9[ij]], acc);
        }
    }
    t6[(size_t)n * HWP + pix] = acc;
}

// ---------------------------------------------------------------------------
// Kernel C2: t9[n,c] = (1/96) * <conv5x5(t1[c]), t6[n]>
// ---------------------------------------------------------------------------
__global__ __launch_bounds__(256) void k_t9(const float* __restrict__ x,
                                            const float* __restrict__ w3,
                                            const float* __restrict__ t6,
                                            float* __restrict__ t9) {
    int n = blockIdx.y, c = blockIdx.x;
    __shared__ float xl[100][100];
    __shared__ float red[4];
    int t = threadIdx.x;
    const float* xc = x + ((size_t)n * CCH + c) * HWP;
    const float* t6n = t6 + (size_t)n * HWP;

    for (int idx = t; idx < 784; idx += 256) {
        if (idx < 400) {
            int r = idx / 100, col = idx - r * 100;
            int row = r < 2 ? r : r + 96;
            xl[row][col] = 0.f;
        } else {
            int rem = idx - 400;
            int h2 = rem >> 2, c4 = rem & 3;
            int col = c4 < 2 ? c4 : c4 + 96;
            xl[2 + h2][col] = 0.f;
        }
    }
    for (int idx = t; idx < HWP; idx += 256) {
        int h = idx / WWID, w = idx - h * WWID;
        int sh = (h == 0) ? (HH - 1) : (h - 1);
        int sw = (w == WWID - 1) ? 0 : (w + 1);
        xl[h + 2][w + 2] = xc[sh * WWID + sw];
    }
    float wv[25];
#pragma unroll
    for (int i = 0; i < 25; i++) wv[i] = w3[c * 25 + i];
    __syncthreads();

    float acc = 0.f;
#pragma unroll
    for (int g = 0; g < 9; g++) {
        int idx = g * 256 + t;
        int h = idx / 24, wg = idx - h * 24;
        int w0 = wg * 4;
        float4 tv = *(const float4*)(t6n + h * WWID + w0);
        float conv[4] = {0.f, 0.f, 0.f, 0.f};
#pragma unroll
        for (int kh = 0; kh < 5; kh++) {
            float4 ra = *(const float4*)&xl[h + kh][w0];
            float4 rb = *(const float4*)&xl[h + kh][w0 + 4];
            float r[8] = {ra.x, ra.y, ra.z, ra.w, rb.x, rb.y, rb.z, rb.w};
#pragma unroll
            for (int kw = 0; kw < 5; kw++) {
                float wk = wv[kh * 5 + kw];
                conv[0] = fmaf(wk, r[kw],     conv[0]);
                conv[1] = fmaf(wk, r[kw + 1], conv[1]);
                conv[2] = fmaf(wk, r[kw + 2], conv[2]);
                conv[3] = fmaf(wk, r[kw + 3], conv[3]);
            }
        }
        acc = fmaf(conv[0], tv.x, acc);
        acc = fmaf(conv[1], tv.y, acc);
        acc = fmaf(conv[2], tv.z, acc);
        acc = fmaf(conv[3], tv.w, acc);
    }
#pragma unroll
    for (int off = 32; off > 0; off >>= 1) acc += __shfl_down(acc, off, 64);
    if ((t & 63) == 0) red[t >> 6] = acc;
    __syncthreads();
    if (t == 0)
        t9[n * 64 + c] = (red[0] + red[1] + red[2] + red[3]) * (1.0f / 96.0f);
}

// ---------------------------------------------------------------------------
// Kernel D: bf16 MFMA GEMM, LDS-free (no barriers).
// out[n,c,s] = t9[n,c] + sum_{k'} t8t[n][c][k'] * B[k'][s],  k' = kk*64+c7
// B[k'][s=r*96+sw] = xt[n][h0+r][sw+2kk-6][c7]  (0 outside w-range, predicated)
// Block = (h-pair, n). Wave: 4 m-tiles x 3 s-tiles, K = 14 chunks of 32.
// ---------------------------------------------------------------------------
__global__ __launch_bounds__(256) void k_out(const short* __restrict__ xt,
                                             const short* __restrict__ t8t,
                                             const float* __restrict__ t9,
                                             float* __restrict__ out) {
    int n = blockIdx.y;
    int h0 = blockIdx.x * 2;
    int t = threadIdx.x, lane = t & 63, wv = t >> 6;
    int q = lane >> 4, sl = lane & 15;

    int sw[3], rr[3];
#pragma unroll
    for (int sj = 0; sj < 3; sj++) {
        int si = wv * 3 + sj;
        rr[sj] = (si >= 6) ? 1 : 0;
        sw[sj] = (si - rr[sj] * 6) * 16 + sl;
    }

    floatx4 acc[4][3] = {};
    const short* A = t8t + (size_t)n * 64 * K7 + sl * K7 + q * 8;
    const short* X0 = xt + ((size_t)n * HH + h0) * (WWID * 64);

    for (int kc = 0; kc < K7; kc += 32) {
        int kk = kc >> 6;
        int c7b = (kc & 63) + q * 8;
        short8 a[4];
#pragma unroll
        for (int mi = 0; mi < 4; mi++)
            a[mi] = *(const short8*)(A + mi * 16 * K7 + kc);
        short8 b[3];
        short8 bz = {};
#pragma unroll
        for (int sj = 0; sj < 3; sj++) {
            int w = sw[sj] + 2 * kk - 6;
            const short8* p = (const short8*)(X0 + ((size_t)(rr[sj] * WWID + w)) * 64 + c7b);
            b[sj] = ((unsigned)w < 96u) ? *p : bz;
        }
#pragma unroll
        for (int mi = 0; mi < 4; mi++)
#pragma unroll
            for (int sj = 0; sj < 3; sj++)
                acc[mi][sj] = __builtin_amdgcn_mfma_f32_16x16x32_bf16(
                    a[mi], b[sj], acc[mi][sj], 0, 0, 0);
    }

    const float* t9n = t9 + n * 64;
#pragma unroll
    for (int mi = 0; mi < 4; mi++) {
#pragma unroll
        for (int i = 0; i < 4; i++) {
            int c = mi * 16 + q * 4 + i;
            float tv = t9n[c];
            float* orow = out + ((size_t)n * CCH + c) * HWP + h0 * WWID;
#pragma unroll
            for (int sj = 0; sj < 3; sj++)
                orow[rr[sj] * WWID + sw[sj]] = acc[mi][sj][i] + tv;
        }
    }
}

// ---------------------------------------------------------------------------
extern "C" void kernel_launch(void* const* d_in, const int* in_sizes, int n_in,
                              void* d_out, int out_size, void* d_ws, size_t ws_size,
                              hipStream_t stream) {
    const float* x  = (const float*)d_in[0];
    const float* w3 = (const float*)d_in[1];
    const float* w4 = (const float*)d_in[2];
    const float* p5 = (const float*)d_in[3];
    const float* p6 = (const float*)d_in[4];
    const float* p8 = (const float*)d_in[5];
    float* out = (float*)d_out;
    float* ws  = (float*)d_ws;

    float* t2p = ws;
    float* t5  = ws + OFF_T5;
    short* t8t = (short*)(ws + OFF_T8);
    float* t6  = ws + OFF_T6;
    float* t9  = ws + OFF_T9;
    short* xt  = (short*)(ws + OFF_XT);

    k_xt<<<dim3(96, 32), 256, 0, stream>>>(x, xt);
    k_t2<<<512, 256, 0, stream>>>(x, t2p);
    k_t5<<<512, 256, 0, stream>>>(t2p, p5, t5);
    k_t8<<<dim3(112, 32), 256, 0, stream>>>(t5, p8, t8t);
    k_t6<<<dim3(36, 32), 256, 0, stream>>>(x, w4, p6, t6);
    k_t9<<<dim3(64, 32), 256, 0, stream>>>(x, w3, t6, t9);
    k_out<<<dim3(48, 32), 256, 0, stream>>>(xt, t8t, t9, out);
}

// Round 4
// 337.413 us; speedup vs baseline: 1.0287x; 1.0287x over previous
//
#include <hip/hip_runtime.h>

#define NB 32
#define CCH 64
#define HH 96
#define WWID 96
#define HWP (HH*WWID)   // 9216
#define K7 448

// ws layout (float offsets):
//   t2p : [32][16][64][64] fp32 partials     = 2,097,152
//   t5  : [32][64][64]                       =   131,072
//   t8t : [32][64][448] bf16 (k'=kk*64+c7)   =   458,752 floats of space
//   t6  : [32][9216]                         =   294,912
//   t9  : [32][64]                           =     2,048
//   wq  : [64][9]  (w4*p6)                   =       576 (+pad)
//   xt  : [32][96][96][64] bf16 (chan-minor) = 9,437,184 floats of space
#define OFF_T5 2097152
#define OFF_T8 2228224
#define OFF_T6 2686976
#define OFF_T9 2981888
#define OFF_WQ 2983936
#define OFF_XT 2984960

typedef __attribute__((ext_vector_type(8))) short short8;
typedef __attribute__((ext_vector_type(4))) float floatx4;

__device__ __forceinline__ short f2bf(float x) {
    unsigned u = __float_as_uint(x);
    unsigned r = (u + 0x7FFF + ((u >> 16) & 1)) >> 16;  // RNE
    return (short)r;
}

// ---------------------------------------------------------------------------
// Kernel XT: xt[n][h][w][c] = bf16(x[n][c][h][w])  (channel-minor transpose)
// ---------------------------------------------------------------------------
__global__ __launch_bounds__(256) void k_xt(const float* __restrict__ x,
                                            short* __restrict__ xt) {
    int n = blockIdx.y, h = blockIdx.x;
    __shared__ float xl[64][97];
    int t = threadIdx.x;
    const float* xn = x + (size_t)n * CCH * HWP + h * WWID;
#pragma unroll
    for (int i = 0; i < 24; i++) {
        int e = i * 256 + t;            // < 6144
        int c = e / 96, w = e - c * 96;
        xl[c][w] = xn[c * HWP + w];
    }
    __syncthreads();
    short* xtn = xt + ((size_t)n * HH + h) * (WWID * 64);
    int c = t & 63, wg = t >> 6;
#pragma unroll
    for (int i = 0; i < 24; i++) {
        int w = i * 4 + wg;
        xtn[w * 64 + c] = f2bf(xl[c][w]);
    }
}

// ---------------------------------------------------------------------------
// Kernel WQ: wq[c][ij] = w4[c][ij] * p6[c]
// ---------------------------------------------------------------------------
__global__ __launch_bounds__(256) void k_wq(const float* __restrict__ w4,
                                            const float* __restrict__ p6,
                                            float* __restrict__ wq) {
    int t = threadIdx.x;
    for (int idx = t; idx < 576; idx += 256)
        wq[idx] = w4[idx] * p6[idx / 9];
}

// ---------------------------------------------------------------------------
// Kernel A: t2 partials via bf16 MFMA, LDS-free.
// ---------------------------------------------------------------------------
__global__ __launch_bounds__(256) void k_t2(const float* __restrict__ x,
                                            float* __restrict__ t2p) {
    int n = blockIdx.x >> 4, ks = blockIdx.x & 15;
    int t = threadIdx.x;
    int wv = t >> 6, lane = t & 63;
    int q = lane >> 4, m = lane & 15;
    const float* xn = x + (size_t)n * CCH * HWP;
    const float* xa = xn + (wv * 16 + m) * HWP;
    floatx4 acc[4] = {};

    int k0 = ks * 576;
    for (int kc = k0; kc < k0 + 576; kc += 32) {
        int h = kc / 96;
        int w0 = kc - h * 96;
        int hr = (h == 0) ? (HH - 1) : (h - 1);
        float4 a0 = *(const float4*)(xa + kc + q * 8);
        float4 a1 = *(const float4*)(xa + kc + q * 8 + 4);
        short8 af = {f2bf(a0.x), f2bf(a0.y), f2bf(a0.z), f2bf(a0.w),
                     f2bf(a1.x), f2bf(a1.y), f2bf(a1.z), f2bf(a1.w)};
#pragma unroll
        for (int j = 0; j < 4; j++) {
            const float* xr = xn + (j * 16 + m) * HWP + hr * 96;
            int base = w0 + q * 8;
            float4 b0 = *(const float4*)(xr + base);
            float4 b1 = *(const float4*)(xr + base + 4);
            int c8 = base + 8;
            float e8 = xr[c8 == 96 ? 0 : c8];
            short8 bf = {f2bf(b0.y), f2bf(b0.z), f2bf(b0.w), f2bf(b1.x),
                         f2bf(b1.y), f2bf(b1.z), f2bf(b1.w), f2bf(e8)};
            acc[j] = __builtin_amdgcn_mfma_f32_16x16x32_bf16(af, bf, acc[j], 0, 0, 0);
        }
    }
    float* o = t2p + ((size_t)(n * 16 + ks)) * 4096;
#pragma unroll
    for (int j = 0; j < 4; j++)
#pragma unroll
        for (int i = 0; i < 4; i++)
            o[(wv * 16 + q * 4 + i) * 64 + j * 16 + m] = acc[j][i];
}

// ---------------------------------------------------------------------------
// Kernel B1: t5[n,b,c] = p5[b,c] * (sum_slices t2p) / 96
// ---------------------------------------------------------------------------
__global__ __launch_bounds__(256) void k_t5(const float* __restrict__ t2p,
                                            const float* __restrict__ p5,
                                            float* __restrict__ t5) {
    int idx = blockIdx.x * 256 + threadIdx.x;
    int n = idx >> 12, rc = idx & 4095;
    float s = 0.f;
#pragma unroll
    for (int sl = 0; sl < 16; sl++)
        s += t2p[((size_t)n * 16 + sl) * 4096 + rc];
    t5[idx] = s * p5[rc] * (1.0f / 96.0f);
}

// ---------------------------------------------------------------------------
// Kernel B2: t8t[n][c][kk*64+c7] = bf16((1/sqrt(448)) * sum_b t5[n,b,c]*p8[b,k])
// ---------------------------------------------------------------------------
__global__ __launch_bounds__(256) void k_t8(const float* __restrict__ t5,
                                            const float* __restrict__ p8,
                                            short* __restrict__ t8t) {
    int n = blockIdx.y;
    int idx = blockIdx.x * 256 + threadIdx.x;   // [0, 448*64)
    int k = idx >> 6, c = idx & 63;
    const float* t5n = t5 + (size_t)n * 4096;
    float s = 0.f;
#pragma unroll 8
    for (int b = 0; b < 64; b++)
        s += t5n[b * 64 + c] * p8[b * K7 + k];
    int c7 = k / 7, kk = k - c7 * 7;
    t8t[((size_t)n * 64 + c) * K7 + kk * 64 + c7] = f2bf(s * 0.04724555912f);
}

// ---------------------------------------------------------------------------
// Kernel C1: t6[n,h,w] = sum_c dwconv3x3_d2(t1; wq)[n,c,h,w]
// ---------------------------------------------------------------------------
__global__ __launch_bounds__(256) void k_t6(const float* __restrict__ x,
                                            const float* __restrict__ wq,
                                            float* __restrict__ t6) {
    int n = blockIdx.y;
    int pix = blockIdx.x * 256 + threadIdx.x;   // < 9216
    int h = pix / WWID, w = pix - h * WWID;

    int off9[9];
    float m9[9];
#pragma unroll
    for (int i = 0; i < 3; i++) {
        int gh = h + (i - 1) * 2;
        bool vr = (gh >= 0) && (gh < HH);
        int srow = vr ? ((gh + HH - 1) % HH) * WWID : 0;
        float rm = vr ? 1.f : 0.f;
#pragma unroll
        for (int j = 0; j < 3; j++) {
            int gw = w + (j - 1) * 2;
            bool vc = (gw >= 0) && (gw < WWID);
            int scol = vc ? (gw + 1) % WWID : 0;
            off9[i * 3 + j] = srow + scol;
            m9[i * 3 + j] = vc ? rm : 0.f;
        }
    }
    const float* xn = x + (size_t)n * CCH * HWP;
    float acc = 0.f;
#pragma unroll 2
    for (int c = 0; c < CCH; c++) {
        const float* xc = xn + c * HWP;
        const float* wc = wq + c * 9;
#pragma unroll
        for (int ij = 0; ij < 9; ij++)
            acc = fmaf(wc[ij] * m9[ij], xc[off9[ij]], acc);
    }
    t6[(size_t)n * HWP + pix] = acc;
}

// ---------------------------------------------------------------------------
// Kernel C2: t9[n,c] = (1/96) * <conv5x5(t1[c]), t6[n]>
// ---------------------------------------------------------------------------
__global__ __launch_bounds__(256) void k_t9(const float* __restrict__ x,
                                            const float* __restrict__ w3,
                                            const float* __restrict__ t6,
                                            float* __restrict__ t9) {
    int n = blockIdx.y, c = blockIdx.x;
    __shared__ float xl[100][100];
    __shared__ float red[4];
    int t = threadIdx.x;
    const float* xc = x + ((size_t)n * CCH + c) * HWP;
    const float* t6n = t6 + (size_t)n * HWP;

    for (int idx = t; idx < 784; idx += 256) {
        if (idx < 400) {
            int r = idx / 100, col = idx - r * 100;
            int row = r < 2 ? r : r + 96;
            xl[row][col] = 0.f;
        } else {
            int rem = idx - 400;
            int h2 = rem >> 2, c4 = rem & 3;
            int col = c4 < 2 ? c4 : c4 + 96;
            xl[2 + h2][col] = 0.f;
        }
    }
    for (int idx = t; idx < HWP; idx += 256) {
        int h = idx / WWID, w = idx - h * WWID;
        int sh = (h == 0) ? (HH - 1) : (h - 1);
        int sw = (w == WWID - 1) ? 0 : (w + 1);
        xl[h + 2][w + 2] = xc[sh * WWID + sw];
    }
    float wv[25];
#pragma unroll
    for (int i = 0; i < 25; i++) wv[i] = w3[c * 25 + i];
    __syncthreads();

    float acc = 0.f;
#pragma unroll
    for (int g = 0; g < 9; g++) {
        int idx = g * 256 + t;
        int h = idx / 24, wg = idx - h * 24;
        int w0 = wg * 4;
        float4 tv = *(const float4*)(t6n + h * WWID + w0);
        float conv[4] = {0.f, 0.f, 0.f, 0.f};
#pragma unroll
        for (int kh = 0; kh < 5; kh++) {
            float4 ra = *(const float4*)&xl[h + kh][w0];
            float4 rb = *(const float4*)&xl[h + kh][w0 + 4];
            float r[8] = {ra.x, ra.y, ra.z, ra.w, rb.x, rb.y, rb.z, rb.w};
#pragma unroll
            for (int kw = 0; kw < 5; kw++) {
                float wk = wv[kh * 5 + kw];
                conv[0] = fmaf(wk, r[kw],     conv[0]);
                conv[1] = fmaf(wk, r[kw + 1], conv[1]);
                conv[2] = fmaf(wk, r[kw + 2], conv[2]);
                conv[3] = fmaf(wk, r[kw + 3], conv[3]);
            }
        }
        acc = fmaf(conv[0], tv.x, acc);
        acc = fmaf(conv[1], tv.y, acc);
        acc = fmaf(conv[2], tv.z, acc);
        acc = fmaf(conv[3], tv.w, acc);
    }
#pragma unroll
    for (int off = 32; off > 0; off >>= 1) acc += __shfl_down(acc, off, 64);
    if ((t & 63) == 0) red[t >> 6] = acc;
    __syncthreads();
    if (t == 0)
        t9[n * 64 + c] = (red[0] + red[1] + red[2] + red[3]) * (1.0f / 96.0f);
}

// ---------------------------------------------------------------------------
// Kernel D: bf16 MFMA GEMM.  B staged in LDS (contiguous copy from xt, padded
// to 68 ch), A preloaded to 56 VGPRs (1 m-tile per wave x 12 s-tiles).
// Per K-chunk: 12 ds_read_b128 + 12 MFMA, zero global traffic.
// ---------------------------------------------------------------------------
__global__ __launch_bounds__(256) void k_out(const short* __restrict__ xt,
                                             const short* __restrict__ t8t,
                                             const float* __restrict__ t9,
                                             float* __restrict__ out) {
    int n = blockIdx.y;
    int h0 = blockIdx.x * 2;
    int t = threadIdx.x, lane = t & 63, wv = t >> 6;
    int q = lane >> 4, sl = lane & 15;

    __shared__ short bsh[2][108][68];   // [r][iw = w+6][c], 136B iw-stride

    // A preload first: latency overlaps staging. row = wv*16+sl, k' = ki*32+q*8+j
    const short* A = t8t + ((size_t)n * 64 + wv * 16 + sl) * K7 + q * 8;
    short8 a[14];
#pragma unroll
    for (int ki = 0; ki < 14; ki++)
        a[ki] = *(const short8*)(A + ki * 32);

    // zero halos: iw in [0,6) U [102,108), 2*12*68 shorts = 816 ints
    for (int idx = t; idx < 816; idx += 256) {
        int p = idx * 2;
        int r = p / (12 * 68);
        int rem = p - r * (12 * 68);
        int iwz = rem / 68, c = rem - iwz * 68;
        int iw = iwz < 6 ? iwz : iwz + 96;
        *(int*)&bsh[r][iw][c] = 0;
    }
    // interior: contiguous copy, 1536 16B chunks
    const short* xtn = xt + ((size_t)n * HH + h0) * (WWID * 64);
    for (int idx = t; idx < 1536; idx += 256) {
        int r = idx / 768;
        int rem = idx - r * 768;
        int w = rem >> 3, c8 = rem & 7;
        short8 v = *(const short8*)(xtn + idx * 8);
        *(short8*)&bsh[r][w + 6][c8 * 8] = v;
    }
    __syncthreads();

    floatx4 acc[12] = {};
#pragma unroll 2
    for (int ki = 0; ki < 14; ki++) {
        int kc = ki * 32;
        int kk = kc >> 6;
        int c7b = (kc & 63) + q * 8;
#pragma unroll
        for (int sj = 0; sj < 12; sj++) {
            int r = sj >= 6 ? 1 : 0;
            int iw = (sj - r * 6) * 16 + sl + 2 * kk;
            short8 b = *(const short8*)&bsh[r][iw][c7b];
            acc[sj] = __builtin_amdgcn_mfma_f32_16x16x32_bf16(a[ki], b, acc[sj], 0, 0, 0);
        }
    }

    // epilogue: D col = sl (s), row = q*4+i (c within wave's m-tile)
    const float* t9n = t9 + n * 64;
    int cb = wv * 16 + q * 4;
#pragma unroll
    for (int i = 0; i < 4; i++) {
        int c = cb + i;
        float tv = t9n[c];
        float* orow = out + ((size_t)n * CCH + c) * HWP + h0 * WWID;
#pragma unroll
        for (int sj = 0; sj < 12; sj++) {
            int r = sj >= 6 ? 1 : 0;
            int sw = (sj - r * 6) * 16 + sl;
            orow[r * WWID + sw] = acc[sj][i] + tv;
        }
    }
}

// ---------------------------------------------------------------------------
extern "C" void kernel_launch(void* const* d_in, const int* in_sizes, int n_in,
                              void* d_out, int out_size, void* d_ws, size_t ws_size,
                              hipStream_t stream) {
    const float* x  = (const float*)d_in[0];
    const float* w3 = (const float*)d_in[1];
    const float* w4 = (const float*)d_in[2];
    const float* p5 = (const float*)d_in[3];
    const float* p6 = (const float*)d_in[4];
    const float* p8 = (const float*)d_in[5];
    float* out = (float*)d_out;
    float* ws  = (float*)d_ws;

    float* t2p = ws;
    float* t5  = ws + OFF_T5;
    short* t8t = (short*)(ws + OFF_T8);
    float* t6  = ws + OFF_T6;
    float* t9  = ws + OFF_T9;
    float* wq  = ws + OFF_WQ;
    short* xt  = (short*)(ws + OFF_XT);

    k_xt<<<dim3(96, 32), 256, 0, stream>>>(x, xt);
    k_wq<<<1, 256, 0, stream>>>(w4, p6, wq);
    k_t2<<<512, 256, 0, stream>>>(x, t2p);
    k_t5<<<512, 256, 0, stream>>>(t2p, p5, t5);
    k_t8<<<dim3(112, 32), 256, 0, stream>>>(t5, p8, t8t);
    k_t6<<<dim3(36, 32), 256, 0, stream>>>(x, wq, t6);
    k_t9<<<dim3(64, 32), 256, 0, stream>>>(x, w3, t6, t9);
    k_out<<<dim3(48, 32), 256, 0, stream>>>(xt, t8t, t9, out);
}

// Round 5
// 313.863 us; speedup vs baseline: 1.1059x; 1.0750x over previous
//
#include <hip/hip_runtime.h>

#define NB 32
#define CCH 64
#define HH 96
#define WWID 96
#define HWP (HH*WWID)   // 9216
#define K7 448

// ws layout (float offsets):
//   t2p : [32][16][64][64] fp32 partials     = 2,097,152
//   t5  : [32][64][64]                       =   131,072
//   t8t : [32][64][448] bf16 (k'=kk*64+c7)   =   458,752 floats of space
//   t6  : [32][9216]                         =   294,912
//   t9  : [32][64]                           =     2,048
//   wqt : [9][64] bf16 (w4*p6, tap-major)    =       512 floats reserved
//   xt  : [32][96][96][64] bf16 (chan-minor) = 9,437,184 floats of space
#define OFF_T5 2097152
#define OFF_T8 2228224
#define OFF_T6 2686976
#define OFF_T9 2981888
#define OFF_WQ 2983936
#define OFF_XT 2984960

typedef __attribute__((ext_vector_type(8))) short short8;
typedef __attribute__((ext_vector_type(4))) float floatx4;

__device__ __forceinline__ short f2bf(float x) {
    unsigned u = __float_as_uint(x);
    unsigned r = (u + 0x7FFF + ((u >> 16) & 1)) >> 16;  // RNE
    return (short)r;
}

// ---------------------------------------------------------------------------
// Kernel XT: xt[n][h][w][c] = bf16(x[n][c][h][w])  (channel-minor transpose)
// ---------------------------------------------------------------------------
__global__ __launch_bounds__(256) void k_xt(const float* __restrict__ x,
                                            short* __restrict__ xt) {
    int n = blockIdx.y, h = blockIdx.x;
    __shared__ float xl[64][97];
    int t = threadIdx.x;
    const float* xn = x + (size_t)n * CCH * HWP + h * WWID;
#pragma unroll
    for (int i = 0; i < 24; i++) {
        int e = i * 256 + t;            // < 6144
        int c = e / 96, w = e - c * 96;
        xl[c][w] = xn[c * HWP + w];
    }
    __syncthreads();
    int* xtn32 = (int*)(xt + ((size_t)n * HH + h) * (WWID * 64));
    int c2 = (t & 31) * 2, wg = t >> 5;   // wg 0..7
#pragma unroll
    for (int i = 0; i < 12; i++) {
        int w = i * 8 + wg;
        unsigned lo = (unsigned short)f2bf(xl[c2][w]);
        unsigned hi = (unsigned short)f2bf(xl[c2 + 1][w]);
        xtn32[(w * 64 + c2) >> 1] = (int)(lo | (hi << 16));
    }
}

// ---------------------------------------------------------------------------
// Kernel WQ: wqt[tap][c] = bf16(w4[c][tap] * p6[c])   (tap-major, bf16)
// ---------------------------------------------------------------------------
__global__ __launch_bounds__(256) void k_wq(const float* __restrict__ w4,
                                            const float* __restrict__ p6,
                                            short* __restrict__ wqt) {
    int t = threadIdx.x;
    for (int idx = t; idx < 576; idx += 256) {
        int tap = idx >> 6, c = idx & 63;
        wqt[idx] = f2bf(w4[c * 9 + tap] * p6[c]);
    }
}

// ---------------------------------------------------------------------------
// Kernel A: t2 partials via bf16 MFMA, LDS-staged.
// t2[n,c,d] = sum_k x[n,c,k] * x[n,d,roll(k)],  K split 16 (576 each, 6 rows,
// 18 chunks of 32).  Tiles: ash/bsh[64][40] bf16 (80B stride: aligned b128,
// ~2-way banks).  Per chunk per wave: 1 A-read + 4 B-reads + 4 MFMA.
// ---------------------------------------------------------------------------
__global__ __launch_bounds__(256) void k_t2(const float* __restrict__ x,
                                            float* __restrict__ t2p) {
    int n = blockIdx.x >> 4, ks = blockIdx.x & 15;
    int t = threadIdx.x;
    int wv = t >> 6, lane = t & 63;
    int q = lane >> 4, m = lane & 15;
    __shared__ short ash[64][40];
    __shared__ short bsh[64][40];
    const float* xn = x + (size_t)n * CCH * HWP;
    int cs = t >> 2, g = t & 3;          // staging role: channel, 8-col group
    const float* xc = xn + cs * HWP;
    floatx4 acc[4] = {};

    for (int ci = 0; ci < 18; ci++) {
        int row_h = ks * 6 + ci / 3;
        int w0 = (ci % 3) * 32;
        int hr = (row_h == 0) ? (HH - 1) : (row_h - 1);
        int base = w0 + g * 8;
        const float* pa = xc + row_h * 96 + base;
        float4 a0 = *(const float4*)pa;
        float4 a1 = *(const float4*)(pa + 4);
        const float* pb = xc + hr * 96 + base;
        float4 b0 = *(const float4*)pb;
        float4 b1 = *(const float4*)(pb + 4);
        float e8 = (base + 8 == 96) ? xc[hr * 96] : pb[8];
        __syncthreads();
        short8 av = {f2bf(a0.x), f2bf(a0.y), f2bf(a0.z), f2bf(a0.w),
                     f2bf(a1.x), f2bf(a1.y), f2bf(a1.z), f2bf(a1.w)};
        short8 bv = {f2bf(b0.y), f2bf(b0.z), f2bf(b0.w), f2bf(b1.x),
                     f2bf(b1.y), f2bf(b1.z), f2bf(b1.w), f2bf(e8)};
        *(short8*)&ash[cs][g * 8] = av;
        *(short8*)&bsh[cs][g * 8] = bv;
        __syncthreads();
        short8 af = *(const short8*)&ash[wv * 16 + m][q * 8];
#pragma unroll
        for (int j = 0; j < 4; j++) {
            short8 bf = *(const short8*)&bsh[j * 16 + m][q * 8];
            acc[j] = __builtin_amdgcn_mfma_f32_16x16x32_bf16(af, bf, acc[j], 0, 0, 0);
        }
    }
    float* o = t2p + ((size_t)(n * 16 + ks)) * 4096;
#pragma unroll
    for (int j = 0; j < 4; j++)
#pragma unroll
        for (int i = 0; i < 4; i++)
            o[(wv * 16 + q * 4 + i) * 64 + j * 16 + m] = acc[j][i];
}

// ---------------------------------------------------------------------------
// Kernel B1: t5[n,b,c] = p5[b,c] * (sum_slices t2p) / 96
// ---------------------------------------------------------------------------
__global__ __launch_bounds__(256) void k_t5(const float* __restrict__ t2p,
                                            const float* __restrict__ p5,
                                            float* __restrict__ t5) {
    int idx = blockIdx.x * 256 + threadIdx.x;
    int n = idx >> 12, rc = idx & 4095;
    float s = 0.f;
#pragma unroll
    for (int sl = 0; sl < 16; sl++)
        s += t2p[((size_t)n * 16 + sl) * 4096 + rc];
    t5[idx] = s * p5[rc] * (1.0f / 96.0f);
}

// ---------------------------------------------------------------------------
// Kernel B2: t8t[n][c][kk*64+c7] = bf16((1/sqrt(448)) * sum_b t5[n,b,c]*p8[b,k])
// ---------------------------------------------------------------------------
__global__ __launch_bounds__(256) void k_t8(const float* __restrict__ t5,
                                            const float* __restrict__ p8,
                                            short* __restrict__ t8t) {
    int n = blockIdx.y;
    int idx = blockIdx.x * 256 + threadIdx.x;   // [0, 448*64)
    int k = idx >> 6, c = idx & 63;
    const float* t5n = t5 + (size_t)n * 4096;
    float s = 0.f;
#pragma unroll 8
    for (int b = 0; b < 64; b++)
        s += t5n[b * 64 + c] * p8[b * K7 + k];
    int c7 = k / 7, kk = k - c7 * 7;
    t8t[((size_t)n * 64 + c) * K7 + kk * 64 + c7] = f2bf(s * 0.04724555912f);
}

// ---------------------------------------------------------------------------
// Kernel C1: t6 via MFMA over xt.  t6[n,s] = sum_{tap,c} wqt[tap,c]*xt[shift(s,tap)][c]
// k = tap*64+c, 18 chunks.  A-frags: contiguous 16B from xt (per-lane predicated
// zero for pad).  B-frags: wqt broadcast.  Wave = 16 consecutive w pixels.
// ---------------------------------------------------------------------------
__global__ __launch_bounds__(256) void k_t6(const short* __restrict__ xt,
                                            const short* __restrict__ wqt,
                                            float* __restrict__ t6) {
    int n = blockIdx.y;
    int t = threadIdx.x, wv = t >> 6, lane = t & 63;
    int q = lane >> 4, m = lane & 15;
    int gidx = blockIdx.x * 4 + wv;      // pixel group (16 px, within one row)
    int pix0 = gidx * 16;
    int h = pix0 / 96, w0 = pix0 - h * 96;
    int w = w0 + m;
    const short* xtn = xt + (size_t)n * HWP * 64;
    floatx4 acc = {};
#pragma unroll
    for (int ci = 0; ci < 18; ci++) {
        int tap = ci >> 1, chalf = (ci & 1) * 32;
        int di = tap / 3 - 1, dj = tap % 3 - 1;
        int gh = h + 2 * di;
        int gw = w + 2 * dj;
        bool valid = ((unsigned)gh < 96u) && ((unsigned)gw < 96u);
        int hr = (gh + 95) % 96;                 // non-negative: gh >= -2
        int wc = gw + 1;
        wc = (wc >= 96) ? (wc - 96) : (wc < 0 ? 0 : wc);
        const short8* pa = (const short8*)(xtn + ((size_t)hr * 96 + wc) * 64 + chalf + q * 8);
        short8 bz = {};
        short8 a = valid ? *pa : bz;
        short8 b = *(const short8*)(wqt + tap * 64 + chalf + q * 8);
        acc = __builtin_amdgcn_mfma_f32_16x16x32_bf16(a, b, acc, 0, 0, 0);
    }
    // D row = pixel (q*4+i), all cols identical; lanes m==0 write.
    if (m == 0) {
        float* t6n = t6 + (size_t)n * HWP + h * 96 + w0;
#pragma unroll
        for (int i = 0; i < 4; i++) t6n[q * 4 + i] = acc[i];
    }
}

// ---------------------------------------------------------------------------
// Kernel C2: t9[n,c] = (1/96) * <conv5x5(t1[c]), t6[n]>
// ---------------------------------------------------------------------------
__global__ __launch_bounds__(256) void k_t9(const float* __restrict__ x,
                                            const float* __restrict__ w3,
                                            const float* __restrict__ t6,
                                            float* __restrict__ t9) {
    int n = blockIdx.y, c = blockIdx.x;
    __shared__ float xl[100][100];
    __shared__ float red[4];
    int t = threadIdx.x;
    const float* xc = x + ((size_t)n * CCH + c) * HWP;
    const float* t6n = t6 + (size_t)n * HWP;

    for (int idx = t; idx < 784; idx += 256) {
        if (idx < 400) {
            int r = idx / 100, col = idx - r * 100;
            int row = r < 2 ? r : r + 96;
            xl[row][col] = 0.f;
        } else {
            int rem = idx - 400;
            int h2 = rem >> 2, c4 = rem & 3;
            int col = c4 < 2 ? c4 : c4 + 96;
            xl[2 + h2][col] = 0.f;
        }
    }
    for (int idx = t; idx < HWP; idx += 256) {
        int h = idx / WWID, w = idx - h * WWID;
        int sh = (h == 0) ? (HH - 1) : (h - 1);
        int sw = (w == WWID - 1) ? 0 : (w + 1);
        xl[h + 2][w + 2] = xc[sh * WWID + sw];
    }
    float wv[25];
#pragma unroll
    for (int i = 0; i < 25; i++) wv[i] = w3[c * 25 + i];
    __syncthreads();

    float acc = 0.f;
#pragma unroll
    for (int g = 0; g < 9; g++) {
        int idx = g * 256 + t;
        int h = idx / 24, wg = idx - h * 24;
        int w0 = wg * 4;
        float4 tv = *(const float4*)(t6n + h * WWID + w0);
        float conv[4] = {0.f, 0.f, 0.f, 0.f};
#pragma unroll
        for (int kh = 0; kh < 5; kh++) {
            float4 ra = *(const float4*)&xl[h + kh][w0];
            float4 rb = *(const float4*)&xl[h + kh][w0 + 4];
            float r[8] = {ra.x, ra.y, ra.z, ra.w, rb.x, rb.y, rb.z, rb.w};
#pragma unroll
            for (int kw = 0; kw < 5; kw++) {
                float wk = wv[kh * 5 + kw];
                conv[0] = fmaf(wk, r[kw],     conv[0]);
                conv[1] = fmaf(wk, r[kw + 1], conv[1]);
                conv[2] = fmaf(wk, r[kw + 2], conv[2]);
                conv[3] = fmaf(wk, r[kw + 3], conv[3]);
            }
        }
        acc = fmaf(conv[0], tv.x, acc);
        acc = fmaf(conv[1], tv.y, acc);
        acc = fmaf(conv[2], tv.z, acc);
        acc = fmaf(conv[3], tv.w, acc);
    }
#pragma unroll
    for (int off = 32; off > 0; off >>= 1) acc += __shfl_down(acc, off, 64);
    if ((t & 63) == 0) red[t >> 6] = acc;
    __syncthreads();
    if (t == 0)
        t9[n * 64 + c] = (red[0] + red[1] + red[2] + red[3]) * (1.0f / 96.0f);
}

// ---------------------------------------------------------------------------
// Kernel D: bf16 MFMA GEMM.  B staged in LDS (contiguous copy from xt, padded
// to 68 ch), A preloaded to 56 VGPRs (1 m-tile per wave x 12 s-tiles).
// ---------------------------------------------------------------------------
__global__ __launch_bounds__(256) void k_out(const short* __restrict__ xt,
                                             const short* __restrict__ t8t,
                                             const float* __restrict__ t9,
                                             float* __restrict__ out) {
    int n = blockIdx.y;
    int h0 = blockIdx.x * 2;
    int t = threadIdx.x, lane = t & 63, wv = t >> 6;
    int q = lane >> 4, sl = lane & 15;

    __shared__ short bsh[2][108][68];   // [r][iw = w+6][c], 136B iw-stride

    const short* A = t8t + ((size_t)n * 64 + wv * 16 + sl) * K7 + q * 8;
    short8 a[14];
#pragma unroll
    for (int ki = 0; ki < 14; ki++)
        a[ki] = *(const short8*)(A + ki * 32);

    for (int idx = t; idx < 816; idx += 256) {
        int p = idx * 2;
        int r = p / (12 * 68);
        int rem = p - r * (12 * 68);
        int iwz = rem / 68, c = rem - iwz * 68;
        int iw = iwz < 6 ? iwz : iwz + 96;
        *(int*)&bsh[r][iw][c] = 0;
    }
    const short* xtn = xt + ((size_t)n * HH + h0) * (WWID * 64);
    for (int idx = t; idx < 1536; idx += 256) {
        int r = idx / 768;
        int rem = idx - r * 768;
        int w = rem >> 3, c8 = rem & 7;
        short8 v = *(const short8*)(xtn + idx * 8);
        *(short8*)&bsh[r][w + 6][c8 * 8] = v;
    }
    __syncthreads();

    floatx4 acc[12] = {};
#pragma unroll 2
    for (int ki = 0; ki < 14; ki++) {
        int kc = ki * 32;
        int kk = kc >> 6;
        int c7b = (kc & 63) + q * 8;
#pragma unroll
        for (int sj = 0; sj < 12; sj++) {
            int r = sj >= 6 ? 1 : 0;
            int iw = (sj - r * 6) * 16 + sl + 2 * kk;
            short8 b = *(const short8*)&bsh[r][iw][c7b];
            acc[sj] = __builtin_amdgcn_mfma_f32_16x16x32_bf16(a[ki], b, acc[sj], 0, 0, 0);
        }
    }

    const float* t9n = t9 + n * 64;
    int cb = wv * 16 + q * 4;
#pragma unroll
    for (int i = 0; i < 4; i++) {
        int c = cb + i;
        float tv = t9n[c];
        float* orow = out + ((size_t)n * CCH + c) * HWP + h0 * WWID;
#pragma unroll
        for (int sj = 0; sj < 12; sj++) {
            int r = sj >= 6 ? 1 : 0;
            int sw = (sj - r * 6) * 16 + sl;
            orow[r * WWID + sw] = acc[sj][i] + tv;
        }
    }
}

// ---------------------------------------------------------------------------
extern "C" void kernel_launch(void* const* d_in, const int* in_sizes, int n_in,
                              void* d_out, int out_size, void* d_ws, size_t ws_size,
                              hipStream_t stream) {
    const float* x  = (const float*)d_in[0];
    const float* w3 = (const float*)d_in[1];
    const float* w4 = (const float*)d_in[2];
    const float* p5 = (const float*)d_in[3];
    const float* p6 = (const float*)d_in[4];
    const float* p8 = (const float*)d_in[5];
    float* out = (float*)d_out;
    float* ws  = (float*)d_ws;

    float* t2p = ws;
    float* t5  = ws + OFF_T5;
    short* t8t = (short*)(ws + OFF_T8);
    float* t6  = ws + OFF_T6;
    float* t9  = ws + OFF_T9;
    short* wqt = (short*)(ws + OFF_WQ);
    short* xt  = (short*)(ws + OFF_XT);

    k_xt<<<dim3(96, 32), 256, 0, stream>>>(x, xt);
    k_wq<<<1, 256, 0, stream>>>(w4, p6, wqt);
    k_t2<<<512, 256, 0, stream>>>(x, t2p);
    k_t5<<<512, 256, 0, stream>>>(t2p, p5, t5);
    k_t8<<<dim3(112, 32), 256, 0, stream>>>(t5, p8, t8t);
    k_t6<<<dim3(144, 32), 256, 0, stream>>>(xt, wqt, t6);
    k_t9<<<dim3(64, 32), 256, 0, stream>>>(x, w3, t6, t9);
    k_out<<<dim3(48, 32), 256, 0, stream>>>(xt, t8t, t9, out);
}